// Round 7
// baseline (384.030 us; speedup 1.0000x reference)
//
#include <hip/hip_runtime.h>

#define HWB   3136
#define SPAD  3364   // 58*58 zero-padded spatial

typedef __attribute__((ext_vector_type(8))) short bf16x8;
typedef __attribute__((ext_vector_type(4))) float f32x4;

__device__ __forceinline__ unsigned short f2bf(float f) {
    unsigned u = __float_as_uint(f);
    unsigned r = (u + 0x7fffu + ((u >> 16) & 1u)) >> 16;
    return (unsigned short)r;
}
__device__ __forceinline__ float bf2f(unsigned short h) {
    return __uint_as_float(((unsigned)h) << 16);
}
__device__ __forceinline__ void gl_lds16(const void* g, void* l) {
    __builtin_amdgcn_global_load_lds(
        (const __attribute__((address_space(1))) void*)g,
        (__attribute__((address_space(3))) void*)l, 16, 0, 0);
}

// ---------------------------------------------------------------------------
// Merged prep (one dispatch, 8240 blocks):
//  [0,6272):    x f32 -> xc bf16 (same layout) + xp bf16 (padded ch-last).
//  [6272,7056): p1 -> p1t transpose.  [7056,7312): wpack.  [7312,8240): border zero.
// ---------------------------------------------------------------------------
__global__ __launch_bounds__(256) void k_prep(
    const float* __restrict__ x, unsigned short* __restrict__ xc,
    unsigned short* __restrict__ xp,
    const float* __restrict__ p1, const float* __restrict__ cw,
    unsigned short* __restrict__ p1t, unsigned short* __restrict__ wp)
{
    const int b = blockIdx.x, t = threadIdx.x;
    if (b < 6272) {
        __shared__ unsigned tile[64 * 33];     // dwords = channel pairs
        const int n = b / 196, rem = b - n * 196;
        const int c0 = (rem / 49) * 64, s0 = (rem % 49) * 64;
        const int cp = t >> 3;                 // 0..31 channel pair
        const int sg = (t & 7) * 8;            // s offset within tile

        const float* src = x + ((size_t)(n * 256 + c0 + 2 * cp)) * HWB + s0 + sg;
        unsigned short b0[8], b1[8];
        {
            float4 v0 = *(const float4*)(src);
            float4 v1 = *(const float4*)(src + 4);
            float4 w0 = *(const float4*)(src + HWB);
            float4 w1 = *(const float4*)(src + HWB + 4);
            b0[0] = f2bf(v0.x); b0[1] = f2bf(v0.y); b0[2] = f2bf(v0.z); b0[3] = f2bf(v0.w);
            b0[4] = f2bf(v1.x); b0[5] = f2bf(v1.y); b0[6] = f2bf(v1.z); b0[7] = f2bf(v1.w);
            b1[0] = f2bf(w0.x); b1[1] = f2bf(w0.y); b1[2] = f2bf(w0.z); b1[3] = f2bf(w0.w);
            b1[4] = f2bf(w1.x); b1[5] = f2bf(w1.y); b1[6] = f2bf(w1.z); b1[7] = f2bf(w1.w);
        }
        unsigned short* xcb = xc + ((size_t)(n * 256 + c0 + 2 * cp)) * HWB + s0 + sg;
        *(bf16x8*)xcb = *(const bf16x8*)&b0[0];
        *(bf16x8*)(xcb + HWB) = *(const bf16x8*)&b1[0];
#pragma unroll
        for (int k = 0; k < 8; ++k)
            tile[(sg + k) * 33 + cp] = (unsigned)b0[k] | ((unsigned)b1[k] << 16);
        __syncthreads();
        const int r = t >> 2;                  // 0..63 local s row
        const int cq = (t & 3) * 8;            // dword col base
        unsigned d[8];
#pragma unroll
        for (int j = 0; j < 8; ++j)
            d[j] = tile[r * 33 + cq + j];
        const int s = s0 + r;
        const int sp = s + 2 * (s / 56) + 59;  // (y+1)*58 + (x+1)
        unsigned* dst = (unsigned*)(xp + ((size_t)n * SPAD + sp) * 256 + c0 + 2 * cq);
        *(uint4*)dst = make_uint4(d[0], d[1], d[2], d[3]);
        *(uint4*)(dst + 4) = make_uint4(d[4], d[5], d[6], d[7]);
    } else if (b < 7056) {
        __shared__ unsigned short tile[32][33];
        const int b2 = b - 6272;
        const int h0 = (b2 % 98) * 32, e0 = (b2 / 98) * 32;
        const int lx = t & 31, ly = t >> 5;
#pragma unroll
        for (int it = 0; it < 4; ++it) {
            int lh = ly + it * 8;
            tile[lh][lx] = f2bf(p1[(size_t)(h0 + lh) * 256 + e0 + lx]);
        }
        __syncthreads();
#pragma unroll
        for (int it = 0; it < 4; ++it) {
            int le = ly + it * 8;
            p1t[(size_t)(e0 + le) * HWB + h0 + lx] = tile[lx][le];
        }
    } else if (b < 7312) {
        const int o = b - 7056;
#pragma unroll
        for (int k = t; k < 1152; k += 256) {
            int tap = k >> 7, ci = k & 127;
            wp[(size_t)o * 1152 + k] = f2bf(cw[(size_t)o * 1152 + ci * 9 + tap]);
        }
    } else {
        const int bb = b - 7312;
        const int n = bb / 29, xb = bb - n * 29;
        const int idx = xb * 256 + t;
        if (idx < 228 * 32) {
            const int i = idx >> 5, ch = idx & 31;
            int sp;
            if (i < 58)       sp = i;
            else if (i < 116) sp = 3306 + (i - 58);
            else if (i < 172) sp = (i - 115) * 58;
            else              sp = (i - 171) * 58 + 57;
            bf16x8 z = {};
            *(bf16x8*)&xp[((size_t)n * SPAD + sp) * 256 + ch * 8] = z;
        }
    }
}

// ---------------------------------------------------------------------------
// GEMM1 (split-K=2): part[z][m][e] = sum_k xc[m][k] p1t[e][k].  256 blocks.
// ---------------------------------------------------------------------------
__global__ __launch_bounds__(256) void k_gemm1(
    const unsigned short* __restrict__ xc, const unsigned short* __restrict__ p1t,
    float* __restrict__ part)
{
    __shared__ short As[2][128 * 64];
    __shared__ short Bs[2][128 * 64];
    const int tid = threadIdx.x;
    const int orig = blockIdx.x;                      // 256 = 8 * 32
    const int wgid = (orig & 7) * 32 + (orig >> 3);
    const int z = wgid >> 7;
    const int rem = wgid & 127;
    const int tileM = (rem >> 1) * 128;
    const int tileN = (rem & 1) * 128;
    const int kbase = z * 1600;
    const int nk = z ? 24 : 25;
    const int wave = tid >> 6, lane = tid & 63;
    const int wm = (wave >> 1) * 64, wn = (wave & 1) * 64;

    const int rl = tid >> 3, q = tid & 7;
    const int swq = (q ^ (rl & 7)) * 8;
    const unsigned short* asrc = xc + (size_t)(tileM + rl) * HWB + kbase + swq;
    const unsigned short* bsrc = p1t + (size_t)(tileN + rl) * HWB + kbase + swq;

    f32x4 acc[4][4] = {};
    const int frow = lane & 15, quad = lane >> 4, sw = frow & 7;
    const int ldst = rl * 64 + q * 8;

#pragma unroll
    for (int p = 0; p < 4; ++p) {
        gl_lds16(asrc + (size_t)(p * 32) * HWB, &As[0][p * 2048 + ldst]);
        gl_lds16(bsrc + (size_t)(p * 32) * HWB, &Bs[0][p * 2048 + ldst]);
    }
    __syncthreads();

    int cur = 0;
    for (int i2 = 0; i2 < nk; ++i2) {
        if (i2 + 1 < nk) {
            const int kn = (i2 + 1) * 64;
#pragma unroll
            for (int p = 0; p < 4; ++p) {
                gl_lds16(asrc + (size_t)(p * 32) * HWB + kn, &As[cur ^ 1][p * 2048 + ldst]);
                gl_lds16(bsrc + (size_t)(p * 32) * HWB + kn, &Bs[cur ^ 1][p * 2048 + ldst]);
            }
        }
        const short* Ab = As[cur];
        const short* Bb = Bs[cur];
#pragma unroll
        for (int h = 0; h < 2; ++h) {
            bf16x8 af[4], bfr[4];
#pragma unroll
            for (int i = 0; i < 4; ++i)
                af[i] = *(const bf16x8*)&Ab[(wm + i * 16 + frow) * 64 + ((h * 4 + quad) ^ sw) * 8];
#pragma unroll
            for (int j = 0; j < 4; ++j)
                bfr[j] = *(const bf16x8*)&Bb[(wn + j * 16 + frow) * 64 + ((h * 4 + quad) ^ sw) * 8];
#pragma unroll
            for (int i = 0; i < 4; ++i)
#pragma unroll
                for (int j = 0; j < 4; ++j)
                    acc[i][j] = __builtin_amdgcn_mfma_f32_16x16x32_bf16(af[i], bfr[j], acc[i][j], 0, 0, 0);
        }
        __syncthreads();
        cur ^= 1;
    }
    float* ob = part + (size_t)z * 8192 * 256;
#pragma unroll
    for (int j = 0; j < 4; ++j) {
        const int e = tileN + wn + j * 16 + frow;
#pragma unroll
        for (int i = 0; i < 4; ++i)
#pragma unroll
            for (int r = 0; r < 4; ++r) {
                int m = tileM + wm + i * 16 + quad * 4 + r;
                ob[(size_t)m * 256 + e] = acc[i][j][r];
            }
    }
}

// ---------------------------------------------------------------------------
// t4scale: reduce 2 split-K slabs; t4h[m][e] = bf16(t1*p4); t5[m]=sum_e t4*p5
// ---------------------------------------------------------------------------
__global__ __launch_bounds__(256) void k_t4scale(
    const float* __restrict__ part, const float* __restrict__ p4,
    const float* __restrict__ p5, unsigned short* __restrict__ t4h,
    float* __restrict__ t5)
{
    const int row = blockIdx.x * 4 + (threadIdx.x >> 6);
    const int lane = threadIdx.x & 63;
    const size_t off = (size_t)row * 256 + lane * 4;
    const size_t slab = (size_t)8192 * 256;
    float4 a0 = *(const float4*)&part[off];
    float4 a1 = *(const float4*)&part[off + slab];
    float4 a;
    a.x = a0.x + a1.x; a.y = a0.y + a1.y; a.z = a0.z + a1.z; a.w = a0.w + a1.w;
    float4 sc = *(const float4*)&p4[(size_t)(row & 255) * 256 + lane * 4];
    float4 pv = *(const float4*)&p5[lane * 4];
    float v0 = a.x * sc.x, v1 = a.y * sc.y, v2 = a.z * sc.z, v3 = a.w * sc.w;
    ushort4 o;
    o.x = f2bf(v0); o.y = f2bf(v1); o.z = f2bf(v2); o.w = f2bf(v3);
    *(ushort4*)&t4h[(size_t)row * 256 + lane * 4] = o;
    float sum = v0 * pv.x + v1 * pv.y + v2 * pv.z + v3 * pv.w;
#pragma unroll
    for (int offd = 32; offd > 0; offd >>= 1) sum += __shfl_down(sum, offd);
    if (lane == 0) t5[row] = sum;
}

// ---------------------------------------------------------------------------
// FUSED conv+bmm per (n, tileS=64).  1568 blocks (no tail: 49*64 = 3136).
//  Phase 1 (g=0,1): conv GEMM 64s x 128o, K=1152, dbuf LDS (48 KB).
//    g0 result parked in 16 packed VGPRs; after g1, both written to t3t
//    (64x256 bf16, 32 KB) which ALIASES the staging LDS (all reads done).
//  Phase 2: out[n][a][s] = t4h[n] (256x256, A-frags direct from L2) @ t3t^T
//           * 0.0625 + t7 (computed in-block from xp . t5).
//  t3 never touches HBM.  LDS ~49.4 KB -> 3 blocks/CU (12 waves).
// ---------------------------------------------------------------------------
__global__ __launch_bounds__(256) void k_convbmm(
    const unsigned short* __restrict__ xp, const unsigned short* __restrict__ wp,
    const unsigned short* __restrict__ t4h, const float* __restrict__ t5,
    float* __restrict__ out)
{
    __shared__ short stg[24576];   // A:[0,4096)x2 | B:[8192,8192+8192)x2 ; t3t=[0,16384)
    __shared__ float t5s[256];
    __shared__ float t7loc[64];
    const int tid = threadIdx.x;
    const int orig = blockIdx.x;                      // 1568 = 8 * 196
    const int wgid = (orig & 7) * 196 + (orig >> 3);
    const int n = wgid / 49;
    const int tileS = (wgid - n * 49) * 64;
    const int wave = tid >> 6, lane = tid & 63;
    const int wm = (wave >> 1) * 32, wn = (wave & 1) * 64;   // conv wave tile 32s x 64o
    const int rl = tid >> 3, q = tid & 7;
    const int swq = (q ^ (rl & 7)) * 8;
    const int ldst = rl * 64 + q * 8;
    const int frow = lane & 15, quad = lane >> 4, sw = frow & 7;

    t5s[tid] = t5[n * 256 + tid];

    // spatial rows for A staging (2 passes x 32 rows); all valid (no tail)
    int spA[2];
#pragma unroll
    for (int p = 0; p < 2; ++p) {
        int s = tileS + p * 32 + rl;
        spA[p] = s + 2 * (s / 56) + 59;
    }

    unsigned pk[2][4][2];          // g0 conv result, bf16-packed
    f32x4 acc[2][4];

    for (int g = 0; g < 2; ++g) {
        const unsigned short* xpn = xp + (size_t)n * SPAD * 256 + g * 128 + swq;
        const unsigned short* arow[2];
        const unsigned short* brow[4];
#pragma unroll
        for (int p = 0; p < 2; ++p) arow[p] = xpn + (size_t)spA[p] * 256;
#pragma unroll
        for (int p = 0; p < 4; ++p)
            brow[p] = wp + (size_t)(g * 128 + p * 32 + rl) * 1152 + swq;
#pragma unroll
        for (int i = 0; i < 2; ++i)
#pragma unroll
            for (int j = 0; j < 4; ++j) acc[i][j] = (f32x4){0.f, 0.f, 0.f, 0.f};

        {   // prologue: tap 0 (dy=-1,dx=-1), kc=0 into buf 0
            const int shift0 = (-59) * 256;
#pragma unroll
            for (int p = 0; p < 2; ++p)
                gl_lds16(arow[p] + shift0, &stg[p * 2048 + ldst]);
#pragma unroll
            for (int p = 0; p < 4; ++p)
                gl_lds16(brow[p], &stg[8192 + p * 2048 + ldst]);
        }
        __syncthreads();

        int cur = 0;
#pragma unroll
        for (int t = 0; t < 18; ++t) {
            if (t < 17) {
                const int tn = t + 1;
                const int tap = tn >> 1;
                const int shift = ((tap / 3 - 1) * 58 + (tap % 3 - 1)) * 256 + (tn & 1) * 64;
#pragma unroll
                for (int p = 0; p < 2; ++p)
                    gl_lds16(arow[p] + shift, &stg[(cur ^ 1) * 4096 + p * 2048 + ldst]);
#pragma unroll
                for (int p = 0; p < 4; ++p)
                    gl_lds16(brow[p] + tn * 64, &stg[8192 + (cur ^ 1) * 8192 + p * 2048 + ldst]);
            }
            const short* Ab = &stg[cur * 4096];
            const short* Bb = &stg[8192 + cur * 8192];
#pragma unroll
            for (int h = 0; h < 2; ++h) {
                bf16x8 af[2], bfr[4];
#pragma unroll
                for (int i = 0; i < 2; ++i)
                    af[i] = *(const bf16x8*)&Ab[(wm + i * 16 + frow) * 64 + ((h * 4 + quad) ^ sw) * 8];
#pragma unroll
                for (int j = 0; j < 4; ++j)
                    bfr[j] = *(const bf16x8*)&Bb[(wn + j * 16 + frow) * 64 + ((h * 4 + quad) ^ sw) * 8];
#pragma unroll
                for (int i = 0; i < 2; ++i)
#pragma unroll
                    for (int j = 0; j < 4; ++j)
                        acc[i][j] = __builtin_amdgcn_mfma_f32_16x16x32_bf16(af[i], bfr[j], acc[i][j], 0, 0, 0);
            }
            __syncthreads();
            cur ^= 1;
        }
        if (g == 0) {   // park g0 in registers (bf16 pairs)
#pragma unroll
            for (int i = 0; i < 2; ++i)
#pragma unroll
                for (int j = 0; j < 4; ++j) {
                    pk[i][j][0] = (unsigned)f2bf(acc[i][j][0]) | ((unsigned)f2bf(acc[i][j][1]) << 16);
                    pk[i][j][1] = (unsigned)f2bf(acc[i][j][2]) | ((unsigned)f2bf(acc[i][j][3]) << 16);
                }
        }
    }

    // ---- write t3t[64][256] (aliases staging; all staging reads barriered) ----
#pragma unroll
    for (int i = 0; i < 2; ++i)
#pragma unroll
        for (int r = 0; r < 4; ++r) {
            const int sLoc = wm + i * 16 + quad * 4 + r;
            const int key = sLoc & 7;
#pragma unroll
            for (int j = 0; j < 4; ++j) {
                const int oc0 = wn + j * 16 + frow;          // g0 column
                const unsigned short v0 = (unsigned short)(pk[i][j][r >> 1] >> ((r & 1) * 16));
                stg[sLoc * 256 + (((oc0 >> 3) ^ key) << 3) + (oc0 & 7)] = (short)v0;
                const int oc1 = 128 + oc0;                   // g1 column
                stg[sLoc * 256 + (((oc1 >> 3) ^ key) << 3) + (oc1 & 7)] = (short)f2bf(acc[i][j][r]);
            }
        }
    // t7 for this s-tile (xp row . t5)
    if (tid < 64) {
        const int s = tileS + tid;
        const int sp = s + 2 * (s / 56) + 59;
        const unsigned short* row = xp + ((size_t)n * SPAD + sp) * 256;
        float accv = 0.f;
#pragma unroll
        for (int j = 0; j < 32; ++j) {
            bf16x8 v = *(const bf16x8*)(row + j * 8);
#pragma unroll
            for (int k = 0; k < 8; ++k)
                accv += t5s[j * 8 + k] * bf2f((unsigned short)v[k]);
        }
        t7loc[tid] = accv * 0.0625f;
    }
    __syncthreads();

    // ---- phase 2: D[256a][64s] = t4h[n] @ t3t^T ----
    const int wm2 = wave * 64;
    f32x4 acc2[4][4] = {};
    const unsigned short* a2 = t4h + ((size_t)n * 256 + wm2 + frow) * 256;
#pragma unroll
    for (int k0 = 0; k0 < 256; k0 += 64) {
#pragma unroll
        for (int h = 0; h < 2; ++h) {
            const int kc8 = (k0 >> 3) + h * 4 + quad;
            bf16x8 af[4], bfr[4];
#pragma unroll
            for (int i = 0; i < 4; ++i)
                af[i] = *(const bf16x8*)&a2[(size_t)i * 16 * 256 + kc8 * 8];
#pragma unroll
            for (int j = 0; j < 4; ++j)
                bfr[j] = *(const bf16x8*)&stg[(j * 16 + frow) * 256 + ((kc8 ^ sw) << 3)];
#pragma unroll
            for (int i = 0; i < 4; ++i)
#pragma unroll
                for (int j = 0; j < 4; ++j)
                    acc2[i][j] = __builtin_amdgcn_mfma_f32_16x16x32_bf16(af[i], bfr[j], acc2[i][j], 0, 0, 0);
        }
    }

    float* ob = out + (size_t)n * 256 * HWB;
#pragma unroll
    for (int j = 0; j < 4; ++j) {
        const int sLoc = j * 16 + frow;
        const int s = tileS + sLoc;
        const float t7v = t7loc[sLoc];
#pragma unroll
        for (int i = 0; i < 4; ++i)
#pragma unroll
            for (int r = 0; r < 4; ++r) {
                const int a = wm2 + i * 16 + quad * 4 + r;
                ob[(size_t)a * HWB + s] = acc2[i][j][r] * 0.0625f + t7v;
            }
    }
}

extern "C" void kernel_launch(void* const* d_in, const int* in_sizes, int n_in,
                              void* d_out, int out_size, void* d_ws, size_t ws_size,
                              hipStream_t stream) {
    const float* x  = (const float*)d_in[0];
    const float* p1 = (const float*)d_in[1];
    const float* cw = (const float*)d_in[2];
    const float* p4 = (const float*)d_in[3];
    const float* p5 = (const float*)d_in[4];

    char* w = (char*)d_ws;
    unsigned short* xp    = (unsigned short*)w;  w += (size_t)32 * SPAD * 256 * 2;   // 55.1 MB
    unsigned short* p1t   = (unsigned short*)w;  w += (size_t)256 * HWB * 2;
    unsigned short* wpack = (unsigned short*)w;  w += (size_t)256 * 1152 * 2;
    unsigned short* t4h   = (unsigned short*)w;  w += (size_t)8192 * 256 * 2;
    float* t5             = (float*)w;           w += (size_t)8192 * 4;

    // d_out doubles as scratch; all scratch consumers (gemm1 reads xc,
    // t4scale reads part) finish before k_convbmm overwrites d_out:
    //   xc   [32][256][3136] bf16 = 51,380,224 B
    //   part [2][8192][256]  f32  = 16,777,216 B  (total 68.2 MB <= 102.8 MB)
    char* o = (char*)d_out;
    unsigned short* xc = (unsigned short*)o;
    float* part        = (float*)(o + (size_t)32 * 256 * HWB * 2);
    float* out = (float*)d_out;

    k_prep    <<<dim3(8240),  256, 0, stream>>>(x, xc, xp, p1, cw, p1t, wpack);
    k_gemm1   <<<dim3(256),   256, 0, stream>>>(xc, p1t, part);
    k_t4scale <<<dim3(2048),  256, 0, stream>>>(part, p4, p5, t4h, t5);
    k_convbmm <<<dim3(1568),  256, 0, stream>>>(xp, wpack, t4h, t5, out);
}

// Round 8
// 322.305 us; speedup vs baseline: 1.1915x; 1.1915x over previous
//
#include <hip/hip_runtime.h>

#define HWB   3136
#define HWPAD 3200
#define SPAD  3364   // 58*58 zero-padded spatial

typedef __attribute__((ext_vector_type(8))) short bf16x8;
typedef __attribute__((ext_vector_type(4))) float f32x4;

__device__ __forceinline__ unsigned short f2bf(float f) {
    unsigned u = __float_as_uint(f);
    unsigned r = (u + 0x7fffu + ((u >> 16) & 1u)) >> 16;
    return (unsigned short)r;
}
__device__ __forceinline__ float bf2f(unsigned short h) {
    return __uint_as_float(((unsigned)h) << 16);
}
__device__ __forceinline__ void gl_lds16(const void* g, void* l) {
    __builtin_amdgcn_global_load_lds(
        (const __attribute__((address_space(1))) void*)g,
        (__attribute__((address_space(3))) void*)l, 16, 0, 0);
}

// ---------------------------------------------------------------------------
// Merged prep (one dispatch, 8240 blocks):
//  [0,6272):    x f32 -> xc bf16 (same layout) + xp bf16 (padded ch-last).
//  [6272,7056): p1 -> p1t transpose.  [7056,7312): wpack.  [7312,8240): border zero.
// ---------------------------------------------------------------------------
__global__ __launch_bounds__(256) void k_prep(
    const float* __restrict__ x, unsigned short* __restrict__ xc,
    unsigned short* __restrict__ xp,
    const float* __restrict__ p1, const float* __restrict__ cw,
    unsigned short* __restrict__ p1t, unsigned short* __restrict__ wp)
{
    const int b = blockIdx.x, t = threadIdx.x;
    if (b < 6272) {
        __shared__ unsigned tile[64 * 33];     // dwords = channel pairs
        const int n = b / 196, rem = b - n * 196;
        const int c0 = (rem / 49) * 64, s0 = (rem % 49) * 64;
        const int cp = t >> 3;                 // 0..31 channel pair
        const int sg = (t & 7) * 8;            // s offset within tile

        const float* src = x + ((size_t)(n * 256 + c0 + 2 * cp)) * HWB + s0 + sg;
        unsigned short b0[8], b1[8];
        {
            float4 v0 = *(const float4*)(src);
            float4 v1 = *(const float4*)(src + 4);
            float4 w0 = *(const float4*)(src + HWB);
            float4 w1 = *(const float4*)(src + HWB + 4);
            b0[0] = f2bf(v0.x); b0[1] = f2bf(v0.y); b0[2] = f2bf(v0.z); b0[3] = f2bf(v0.w);
            b0[4] = f2bf(v1.x); b0[5] = f2bf(v1.y); b0[6] = f2bf(v1.z); b0[7] = f2bf(v1.w);
            b1[0] = f2bf(w0.x); b1[1] = f2bf(w0.y); b1[2] = f2bf(w0.z); b1[3] = f2bf(w0.w);
            b1[4] = f2bf(w1.x); b1[5] = f2bf(w1.y); b1[6] = f2bf(w1.z); b1[7] = f2bf(w1.w);
        }
        unsigned short* xcb = xc + ((size_t)(n * 256 + c0 + 2 * cp)) * HWB + s0 + sg;
        *(bf16x8*)xcb = *(const bf16x8*)&b0[0];
        *(bf16x8*)(xcb + HWB) = *(const bf16x8*)&b1[0];
#pragma unroll
        for (int k = 0; k < 8; ++k)
            tile[(sg + k) * 33 + cp] = (unsigned)b0[k] | ((unsigned)b1[k] << 16);
        __syncthreads();
        const int r = t >> 2;                  // 0..63 local s row
        const int cq = (t & 3) * 8;            // dword col base
        unsigned d[8];
#pragma unroll
        for (int j = 0; j < 8; ++j)
            d[j] = tile[r * 33 + cq + j];
        const int s = s0 + r;
        const int sp = s + 2 * (s / 56) + 59;  // (y+1)*58 + (x+1)
        unsigned* dst = (unsigned*)(xp + ((size_t)n * SPAD + sp) * 256 + c0 + 2 * cq);
        *(uint4*)dst = make_uint4(d[0], d[1], d[2], d[3]);
        *(uint4*)(dst + 4) = make_uint4(d[4], d[5], d[6], d[7]);
    } else if (b < 7056) {
        __shared__ unsigned short tile[32][33];
        const int b2 = b - 6272;
        const int h0 = (b2 % 98) * 32, e0 = (b2 / 98) * 32;
        const int lx = t & 31, ly = t >> 5;
#pragma unroll
        for (int it = 0; it < 4; ++it) {
            int lh = ly + it * 8;
            tile[lh][lx] = f2bf(p1[(size_t)(h0 + lh) * 256 + e0 + lx]);
        }
        __syncthreads();
#pragma unroll
        for (int it = 0; it < 4; ++it) {
            int le = ly + it * 8;
            p1t[(size_t)(e0 + le) * HWB + h0 + lx] = tile[lx][le];
        }
    } else if (b < 7312) {
        const int o = b - 7056;
#pragma unroll
        for (int k = t; k < 1152; k += 256) {
            int tap = k >> 7, ci = k & 127;
            wp[(size_t)o * 1152 + k] = f2bf(cw[(size_t)o * 1152 + ci * 9 + tap]);
        }
    } else {
        const int bb = b - 7312;
        const int n = bb / 29, xb = bb - n * 29;
        const int idx = xb * 256 + t;
        if (idx < 228 * 32) {
            const int i = idx >> 5, ch = idx & 31;
            int sp;
            if (i < 58)       sp = i;
            else if (i < 116) sp = 3306 + (i - 58);
            else if (i < 172) sp = (i - 115) * 58;
            else              sp = (i - 171) * 58 + 57;
            bf16x8 z = {};
            *(bf16x8*)&xp[((size_t)n * SPAD + sp) * 256 + ch * 8] = z;
        }
    }
}

// ---------------------------------------------------------------------------
// Merged MFMA dispatch (1728 blocks):
//  [0,128):     GEMM1 split-K=1 (K=3136, 49 steps) with FUSED t4scale
//               epilogue: t4h[m][e] = bf16(acc*p4), t5[m] += partial (atomic;
//               exactly 2 commutative adds per entry -> deterministic).
//               Placed FIRST so the long-K blocks start at t=0.
//  [128,1728):  grouped 3x3 conv GEMM per (n,g), K=1152, XCD-swizzled,
//               double-buffered LDS (the proven 76us kernel, unchanged).
// ---------------------------------------------------------------------------
__global__ __launch_bounds__(256) void k_mfma(
    const unsigned short* __restrict__ xp, const unsigned short* __restrict__ wp,
    unsigned short* __restrict__ t3cl,
    const unsigned short* __restrict__ xc, const unsigned short* __restrict__ p1t,
    const float* __restrict__ p4, const float* __restrict__ p5,
    unsigned short* __restrict__ t4h, float* __restrict__ t5)
{
    __shared__ short As[2][128 * 64];
    __shared__ short Bs[2][128 * 64];
    const int tid = threadIdx.x;
    const int wave = tid >> 6, lane = tid & 63;
    const int wm = (wave >> 1) * 64, wn = (wave & 1) * 64;
    const int rl = tid >> 3, q = tid & 7;
    const int swq = (q ^ (rl & 7)) * 8;
    const int ldst = rl * 64 + q * 8;
    const int frow = lane & 15, quad = lane >> 4, sw = frow & 7;

    if (blockIdx.x >= 128) {
        // ----- conv -----
        const int orig = blockIdx.x - 128;                 // 1600 = 8 * 200
        const int wgid = (orig & 7) * 200 + (orig >> 3);
        const int ng = wgid / 25;
        const int tileS = (wgid - ng * 25) * 128;
        const int n = ng >> 1, g = ng & 1;

        const unsigned short* xpn = xp + (size_t)n * SPAD * 256 + g * 128 + swq;
        const unsigned short* arow[4];
        const unsigned short* brow[4];
#pragma unroll
        for (int p = 0; p < 4; ++p) {
            int s = tileS + p * 32 + rl;
            int sc = s < HWB ? s : HWB - 1;
            int sp = sc + 2 * (sc / 56) + 59;
            arow[p] = xpn + (size_t)sp * 256;
            brow[p] = wp + (size_t)(g * 128 + p * 32 + rl) * 1152 + swq;
        }

        f32x4 acc[4][4] = {};
        int rofA[4], rofB[4];
#pragma unroll
        for (int i = 0; i < 4; ++i) {
            rofA[i] = (wm + i * 16 + frow) * 64;
            rofB[i] = (wn + i * 16 + frow) * 64;
        }
        {
            const int shift0 = (-59) * 256;
#pragma unroll
            for (int p = 0; p < 4; ++p) {
                gl_lds16(arow[p] + shift0, &As[0][p * 2048 + ldst]);
                gl_lds16(brow[p], &Bs[0][p * 2048 + ldst]);
            }
        }
        __syncthreads();

        int cur = 0;
#pragma unroll
        for (int t = 0; t < 18; ++t) {
            if (t < 17) {
                const int tn = t + 1;
                const int tap = tn >> 1;
                const int shift = ((tap / 3 - 1) * 58 + (tap % 3 - 1)) * 256 + (tn & 1) * 64;
#pragma unroll
                for (int p = 0; p < 4; ++p) {
                    gl_lds16(arow[p] + shift, &As[cur ^ 1][p * 2048 + ldst]);
                    gl_lds16(brow[p] + tn * 64, &Bs[cur ^ 1][p * 2048 + ldst]);
                }
            }
            const short* Ab = As[cur];
            const short* Bb = Bs[cur];
#pragma unroll
            for (int h = 0; h < 2; ++h) {
                bf16x8 af[4], bfr[4];
#pragma unroll
                for (int i = 0; i < 4; ++i)
                    af[i] = *(const bf16x8*)&Ab[rofA[i] + ((h * 4 + quad) ^ sw) * 8];
#pragma unroll
                for (int j = 0; j < 4; ++j)
                    bfr[j] = *(const bf16x8*)&Bb[rofB[j] + ((h * 4 + quad) ^ sw) * 8];
#pragma unroll
                for (int i = 0; i < 4; ++i)
#pragma unroll
                    for (int j = 0; j < 4; ++j)
                        acc[i][j] = __builtin_amdgcn_mfma_f32_16x16x32_bf16(af[i], bfr[j], acc[i][j], 0, 0, 0);
            }
            __syncthreads();
            cur ^= 1;
        }
        unsigned short* ob = t3cl + (size_t)n * HWPAD * 256 + g * 128;
#pragma unroll
        for (int i = 0; i < 4; ++i)
#pragma unroll
            for (int r = 0; r < 4; ++r) {
                int s = tileS + wm + i * 16 + quad * 4 + r;
                int c = wn + frow;
#pragma unroll
                for (int j = 0; j < 4; ++j) {
                    float v = (s < HWB) ? acc[i][j][r] : 0.f;
                    ob[(size_t)s * 256 + c + j * 16] = f2bf(v);
                }
            }
    } else {
        // ----- gemm1 (split-K=1, fused t4scale epilogue) -----
        const int orig = blockIdx.x;                      // 128 = 8 * 16
        const int wgid = (orig & 7) * 16 + (orig >> 3);
        const int tileM = (wgid >> 1) * 128;
        const int tileN = (wgid & 1) * 128;

        const unsigned short* asrc = xc + (size_t)(tileM + rl) * HWB + swq;
        const unsigned short* bsrc = p1t + (size_t)(tileN + rl) * HWB + swq;

        f32x4 acc[4][4] = {};
#pragma unroll
        for (int p = 0; p < 4; ++p) {
            gl_lds16(asrc + (size_t)(p * 32) * HWB, &As[0][p * 2048 + ldst]);
            gl_lds16(bsrc + (size_t)(p * 32) * HWB, &Bs[0][p * 2048 + ldst]);
        }
        __syncthreads();

        int cur = 0;
        for (int i2 = 0; i2 < 49; ++i2) {
            if (i2 + 1 < 49) {
                const int kn = (i2 + 1) * 64;
#pragma unroll
                for (int p = 0; p < 4; ++p) {
                    gl_lds16(asrc + (size_t)(p * 32) * HWB + kn, &As[cur ^ 1][p * 2048 + ldst]);
                    gl_lds16(bsrc + (size_t)(p * 32) * HWB + kn, &Bs[cur ^ 1][p * 2048 + ldst]);
                }
            }
            const short* Ab = As[cur];
            const short* Bb = Bs[cur];
#pragma unroll
            for (int h = 0; h < 2; ++h) {
                bf16x8 af[4], bfr[4];
#pragma unroll
                for (int i = 0; i < 4; ++i)
                    af[i] = *(const bf16x8*)&Ab[(wm + i * 16 + frow) * 64 + ((h * 4 + quad) ^ sw) * 8];
#pragma unroll
                for (int j = 0; j < 4; ++j)
                    bfr[j] = *(const bf16x8*)&Bb[(wn + j * 16 + frow) * 64 + ((h * 4 + quad) ^ sw) * 8];
#pragma unroll
                for (int i = 0; i < 4; ++i)
#pragma unroll
                    for (int j = 0; j < 4; ++j)
                        acc[i][j] = __builtin_amdgcn_mfma_f32_16x16x32_bf16(af[i], bfr[j], acc[i][j], 0, 0, 0);
            }
            __syncthreads();
            cur ^= 1;
        }
        // fused t4scale: t4h = bf16(acc*p4); t5[m] += sum_e t4*p5 (partial)
        float p5v[4];
#pragma unroll
        for (int j = 0; j < 4; ++j)
            p5v[j] = p5[tileN + wn + j * 16 + frow];
#pragma unroll
        for (int i = 0; i < 4; ++i)
#pragma unroll
            for (int r = 0; r < 4; ++r) {
                const int m = tileM + wm + i * 16 + quad * 4 + r;
                const float* p4row = p4 + (size_t)(m & 255) * 256;
                float s = 0.f;
#pragma unroll
                for (int j = 0; j < 4; ++j) {
                    const int e = tileN + wn + j * 16 + frow;
                    const float t4v = acc[i][j][r] * p4row[e];
                    t4h[(size_t)m * 256 + e] = f2bf(t4v);
                    s += t4v * p5v[j];
                }
#pragma unroll
                for (int off = 1; off < 16; off <<= 1)
                    s += __shfl_xor(s, off);
                if (frow == 0) atomicAdd(&t5[m], s);
            }
    }
}

// ---------------------------------------------------------------------------
// BMM: out[n][a][s] = (sum_b t4h[n][a][b] * t3cl[n][s][b]) / 16 + t7[n][s]
// t7 computed in-kernel from xp row dot t5.  XCD-swizzled; double-buffered.
// ---------------------------------------------------------------------------
__global__ __launch_bounds__(256) void k_bmm(
    const unsigned short* __restrict__ t4h, const unsigned short* __restrict__ t3cl,
    const unsigned short* __restrict__ xp, const float* __restrict__ t5,
    float* __restrict__ out)
{
    __shared__ short As[2][128 * 64];
    __shared__ short Bs[2][128 * 64];
    __shared__ float t5s[256];
    __shared__ float t7loc[128];
    const int tid = threadIdx.x;
    const int orig = blockIdx.x;                       // 1600 = 8 * 200
    const int wgid = (orig & 7) * 200 + (orig >> 3);
    const int n = wgid / 50;
    const int rem = wgid - n * 50;
    const int tileA = (rem / 25) * 128;
    const int tileS = (rem % 25) * 128;
    const int wave = tid >> 6, lane = tid & 63;
    const int wm = (wave >> 1) * 64, wn = (wave & 1) * 64;

    const int rl = tid >> 3, q = tid & 7;
    const int swq = (q ^ (rl & 7)) * 8;
    const unsigned short* asrc = t4h + ((size_t)n * 256 + tileA + rl) * 256 + swq;
    const unsigned short* bsrc = t3cl + ((size_t)n * HWPAD + tileS + rl) * 256 + swq;

    f32x4 acc[4][4] = {};
    const int frow = lane & 15, quad = lane >> 4, sw = frow & 7;
    const int ldst = rl * 64 + q * 8;

    t5s[tid] = t5[n * 256 + tid];
#pragma unroll
    for (int p = 0; p < 4; ++p) {
        gl_lds16(asrc + (size_t)(p * 32) * 256, &As[0][p * 2048 + ldst]);
        gl_lds16(bsrc + (size_t)(p * 32) * 256, &Bs[0][p * 2048 + ldst]);
    }
    __syncthreads();   // t5s visible; buf0 staged

    if (tid < 128) {
        const int s = tileS + tid;
        float accv = 0.f;
        if (s < HWB) {
            const int sp = s + 2 * (s / 56) + 59;
            const unsigned short* row = xp + ((size_t)n * SPAD + sp) * 256;
#pragma unroll
            for (int j = 0; j < 32; ++j) {
                bf16x8 v = *(const bf16x8*)(row + j * 8);
#pragma unroll
                for (int k = 0; k < 8; ++k)
                    accv += t5s[j * 8 + k] * bf2f((unsigned short)v[k]);
            }
        }
        t7loc[tid] = accv * 0.0625f;
    }

    int cur = 0;
#pragma unroll
    for (int k0 = 0; k0 < 256; k0 += 64) {
        if (k0 < 192) {
            const int kn = k0 + 64;
#pragma unroll
            for (int p = 0; p < 4; ++p) {
                gl_lds16(asrc + (size_t)(p * 32) * 256 + kn, &As[cur ^ 1][p * 2048 + ldst]);
                gl_lds16(bsrc + (size_t)(p * 32) * 256 + kn, &Bs[cur ^ 1][p * 2048 + ldst]);
            }
        }
        const short* Ab = As[cur];
        const short* Bb = Bs[cur];
#pragma unroll
        for (int h = 0; h < 2; ++h) {
            bf16x8 af[4], bfr[4];
#pragma unroll
            for (int i = 0; i < 4; ++i)
                af[i] = *(const bf16x8*)&Ab[(wm + i * 16 + frow) * 64 + ((h * 4 + quad) ^ sw) * 8];
#pragma unroll
            for (int j = 0; j < 4; ++j)
                bfr[j] = *(const bf16x8*)&Bb[(wn + j * 16 + frow) * 64 + ((h * 4 + quad) ^ sw) * 8];
#pragma unroll
            for (int i = 0; i < 4; ++i)
#pragma unroll
                for (int j = 0; j < 4; ++j)
                    acc[i][j] = __builtin_amdgcn_mfma_f32_16x16x32_bf16(af[i], bfr[j], acc[i][j], 0, 0, 0);
        }
        __syncthreads();
        cur ^= 1;
    }
    float* ob = out + (size_t)n * 256 * HWB;
#pragma unroll
    for (int j = 0; j < 4; ++j) {
        const int sLoc = wn + j * 16 + frow;
        const int s = tileS + sLoc;
        if (s >= HWB) continue;
        const float t7v = t7loc[sLoc];
#pragma unroll
        for (int i = 0; i < 4; ++i)
#pragma unroll
            for (int r = 0; r < 4; ++r) {
                int a = tileA + wm + i * 16 + quad * 4 + r;
                ob[(size_t)a * HWB + s] = acc[i][j][r] * 0.0625f + t7v;
            }
    }
}

extern "C" void kernel_launch(void* const* d_in, const int* in_sizes, int n_in,
                              void* d_out, int out_size, void* d_ws, size_t ws_size,
                              hipStream_t stream) {
    const float* x  = (const float*)d_in[0];
    const float* p1 = (const float*)d_in[1];
    const float* cw = (const float*)d_in[2];
    const float* p4 = (const float*)d_in[3];
    const float* p5 = (const float*)d_in[4];

    char* w = (char*)d_ws;
    unsigned short* xp    = (unsigned short*)w;  w += (size_t)32 * SPAD * 256 * 2;   // 55.1 MB
    unsigned short* t3cl  = (unsigned short*)w;  w += (size_t)32 * HWPAD * 256 * 2;  // 52.4 MB
    unsigned short* p1t   = (unsigned short*)w;  w += (size_t)256 * HWB * 2;
    unsigned short* wpack = (unsigned short*)w;  w += (size_t)256 * 1152 * 2;
    unsigned short* t4h   = (unsigned short*)w;  w += (size_t)8192 * 256 * 2;
    float* t5             = (float*)w;           w += (size_t)8192 * 4;

    // d_out doubles as scratch; xc's only consumer (k_mfma) finishes before
    // k_bmm overwrites d_out:  xc [32][256][3136] bf16 = 51.4 MB <= 102.8 MB
    char* o = (char*)d_out;
    unsigned short* xc = (unsigned short*)o;
    float* out = (float*)d_out;

    hipMemsetAsync(t5, 0, (size_t)8192 * 4, stream);
    k_prep <<<dim3(8240), 256, 0, stream>>>(x, xc, xp, p1, cw, p1t, wpack);
    k_mfma <<<dim3(1728), 256, 0, stream>>>(xp, wpack, t3cl, xc, p1t, p4, p5, t4h, t5);
    k_bmm  <<<dim3(1600), 256, 0, stream>>>(t4h, t3cl, xp, t5, out);
}